// Round 13
// baseline (70.590 us; speedup 1.0000x reference)
//
#include <hip/hip_runtime.h>
#include <cstdint>

#define HW 4096
#define C_ 256
#define NN 49
#define KW 305    // 49 + 256 (original fixup w1 row length)

typedef __bf16 bf16;
typedef bf16 bf16x8 __attribute__((ext_vector_type(8)));
typedef bf16 bf16x4 __attribute__((ext_vector_type(4)));
typedef float f32x4 __attribute__((ext_vector_type(4)));

#define GLD16(src, dst) __builtin_amdgcn_global_load_lds( \
    (const __attribute__((address_space(1))) uint32_t*)(src), \
    (__attribute__((address_space(3))) uint32_t*)(dst), 16, 0, 0)

__device__ __forceinline__ int refl(int i) { return i < 0 ? -i : (i > 63 ? 126 - i : i); }
__device__ __forceinline__ float sigmoidf_(float x) { return 1.f / (1.f + __expf(-x)); }

// ---------------------------------------------------------------- setup: cvtT + all weight prep, one launch
__global__ __launch_bounds__(256) void setup_k(const float* __restrict__ spatial,
                                               const float* __restrict__ semantic,
                                               const float* __restrict__ rp_w1,
                                               const float* __restrict__ rp_w2,
                                               const float* __restrict__ op_w1,
                                               const float* __restrict__ op_w2,
                                               const float* __restrict__ fp_w1,
                                               const float* __restrict__ fp_w2,
                                               const float* __restrict__ sigma,
                                               bf16* __restrict__ spb, bf16* __restrict__ seb,
                                               bf16* __restrict__ wrp1, bf16* __restrict__ wrp2,
                                               bf16* __restrict__ wop1, bf16* __restrict__ wop2,
                                               bf16* __restrict__ w1ckb, bf16* __restrict__ w1sb,
                                               bf16* __restrict__ w2Tg, float* __restrict__ sk)
{
    __shared__ float tile[32][33];
    const int bid = blockIdx.x, t = threadIdx.x;
    if (bid < 4096) {
        int z = bid >> 10, r = bid & 1023;
        int b = z & 1;
        const float* src = (z >> 1) ? semantic : spatial;
        bf16* dst = (z >> 1) ? seb : spb;
        int p0 = (r & 127) * 32, c0 = (r >> 7) * 32;
        int tx = t & 31, ty = t >> 5;
        const float* s = src + (size_t)b * C_ * HW;
        #pragma unroll
        for (int i = 0; i < 32; i += 8)
            tile[ty + i][tx] = s[(size_t)(c0 + ty + i) * HW + p0 + tx];
        __syncthreads();
        int p = t >> 3, cq = (t & 7) * 4;
        bf16x4 o = {(bf16)tile[cq][p], (bf16)tile[cq + 1][p], (bf16)tile[cq + 2][p], (bf16)tile[cq + 3][p]};
        *(bf16x4*)&dst[((size_t)b * HW + p0 + p) * C_ + c0 + cq] = o;
        return;
    }
    int pid = bid - 4096;
    if (pid < 256) {
        const float* src = (pid < 64) ? rp_w1 : (pid < 128) ? rp_w2 : (pid < 192) ? op_w1 : op_w2;
        bf16* dst = (pid < 64) ? wrp1 : (pid < 128) ? wrp2 : (pid < 192) ? wop1 : wop2;
        int i = ((pid & 63) * 256 + t) * 4;
        f32x4 v = *(const f32x4*)&src[i];
        bf16x4 o = {(bf16)v[0], (bf16)v[1], (bf16)v[2], (bf16)v[3]};
        *(bf16x4*)&dst[i] = o;
    } else if (pid == 256) {
        if (t < NN) {
            int i = t / 7, j = t % 7;
            float xg = (i - 3) * (1.f / 3.f), yg = (j - 3) * (1.f / 3.f);
            float s = sigma[0];
            sk[t] = __expf(-(xg * xg + yg * yg) / (2.f * s * s));
        }
    } else if (pid < 270) {
        int idx = (pid - 257) * 256 + t;
        if (idx < NN * 64) {
            int k = idx >> 6, o = idx & 63;
            w1ckb[idx] = (o < NN) ? (bf16)fp_w1[o * KW + k] : (bf16)0.f;
        }
    } else if (pid < 334) {
        int idx = (pid - 270) * 256 + t;
        int o = idx >> 8, c = idx & 255;
        w1sb[idx] = (o < NN) ? (bf16)fp_w1[o * KW + NN + c] : (bf16)0.f;
    } else {
        int idx = (pid - 334) * 256 + t;
        if (idx < NN * 64) {
            int k = idx >> 6, o = idx & 63;
            w2Tg[idx] = (o < NN) ? (bf16)fp_w2[o * NN + k] : (bf16)0.f;
        }
    }
}

// ---------------------------------------------------------------- B-chunk staging (256 threads): 256 out x 32 k
__device__ __forceinline__ void stage_b(const bf16* __restrict__ Wp, bf16* dst, int kc, int t)
{
    const bf16* gB = Wp + (size_t)(t >> 2) * C_ + kc + (((t & 3) ^ ((t >> 3) & 3)) * 8);
    #pragma unroll
    for (int ii = 0; ii < 4; ++ii)
        GLD16(gB + (size_t)ii * 64 * C_, dst + ii * 2048 + t * 8);
}

// ---------------------------------------------------------------- B-chunk staging (512 threads): 256 out x 32 k
// each GLD16 round covers 512 thr x 8 bf16 = 4096 elements (rows 0..127, then 128..255)
__device__ __forceinline__ void stage_b512(const bf16* __restrict__ Wp, bf16* dst, int kc, int t)
{
    const bf16* gB = Wp + (size_t)(t >> 2) * C_ + kc + (((t & 3) ^ ((t >> 3) & 3)) * 8);
    GLD16(gB, dst + t * 8);
    GLD16(gB + (size_t)128 * C_, dst + 4096 + t * 8);
}

// ---------------------------------------------------------------- fused conv1x1 -> LN(+SiLU) -> conv1x1, 32 px/block
template<bool SILU, int MODE>
__global__ __launch_bounds__(256) void conv_pair(const bf16* __restrict__ X,
                                                 const bf16* __restrict__ W1,
                                                 const float* __restrict__ b1v,
                                                 const float* __restrict__ g,
                                                 const float* __restrict__ be,
                                                 const bf16* __restrict__ W2,
                                                 const float* __restrict__ b2v,
                                                 void* __restrict__ Yv)
{
    __shared__ __align__(16) bf16 Xf[32 * 256];
    __shared__ __align__(16) bf16 Mid[32 * 256];
    __shared__ __align__(16) bf16 Bs[2][256 * 32];
    __shared__ float lnred[32][4][2];
    const int t = threadIdx.x;
    const int lane = t & 63, wc = t >> 6;
    const int l15 = lane & 15, kb = lane >> 4;
    const long q0 = (long)blockIdx.x * 32;

    {
        const int r8 = t >> 5, slot = t & 31;
        const bf16* gX = X + (q0 + r8) * C_ + ((slot ^ (r8 & 7)) * 8);
        #pragma unroll
        for (int i = 0; i < 4; ++i)
            GLD16(gX + (size_t)i * 8 * C_, &Xf[i * 2048 + t * 8]);
    }
    stage_b(W1, &Bs[0][0], 0, t);

    const int x7 = l15 & 7;
    const int bsl = (kb ^ ((l15 >> 1) & 3)) * 8;
    int boff[4];
    #pragma unroll
    for (int n = 0; n < 4; ++n)
        boff[n] = (wc * 64 + n * 16 + l15) * 32 + bsl;
    const int a0base = l15 * 256;
    const int a1base = (16 + l15) * 256;

    f32x4 acc[2][4];
    #pragma unroll
    for (int m = 0; m < 2; ++m)
        #pragma unroll
        for (int n = 0; n < 4; ++n) acc[m][n] = (f32x4){0.f, 0.f, 0.f, 0.f};

    __syncthreads();
    int cur = 0;
    #pragma unroll
    for (int ks = 0; ks < 8; ++ks) {
        if (ks < 7) stage_b(W1, &Bs[cur ^ 1][0], (ks + 1) * 32, t);
        const int ko = ((ks * 4 + kb) ^ x7) * 8;
        bf16x8 a0 = *(const bf16x8*)&Xf[a0base + ko];
        bf16x8 a1 = *(const bf16x8*)&Xf[a1base + ko];
        #pragma unroll
        for (int n = 0; n < 4; ++n) {
            bf16x8 b = *(const bf16x8*)&Bs[cur][boff[n]];
            acc[0][n] = __builtin_amdgcn_mfma_f32_16x16x32_bf16(a0, b, acc[0][n], 0, 0, 0);
            acc[1][n] = __builtin_amdgcn_mfma_f32_16x16x32_bf16(a1, b, acc[1][n], 0, 0, 0);
        }
        __syncthreads();
        cur ^= 1;
    }

    stage_b(W2, &Bs[0][0], 0, t);

    float s4[2][4], ss4[2][4];
    #pragma unroll
    for (int m = 0; m < 2; ++m)
        #pragma unroll
        for (int r = 0; r < 4; ++r) { s4[m][r] = 0.f; ss4[m][r] = 0.f; }
    #pragma unroll
    for (int n = 0; n < 4; ++n) {
        float bo = b1v[wc * 64 + n * 16 + l15];
        #pragma unroll
        for (int m = 0; m < 2; ++m)
            #pragma unroll
            for (int r = 0; r < 4; ++r) {
                float v = acc[m][n][r] + bo;
                acc[m][n][r] = v;
                s4[m][r] += v; ss4[m][r] += v * v;
            }
    }
    #pragma unroll
    for (int off = 1; off <= 8; off <<= 1)
        #pragma unroll
        for (int m = 0; m < 2; ++m)
            #pragma unroll
            for (int r = 0; r < 4; ++r) {
                s4[m][r]  += __shfl_xor(s4[m][r], off, 64);
                ss4[m][r] += __shfl_xor(ss4[m][r], off, 64);
            }
    if (l15 == 0) {
        #pragma unroll
        for (int m = 0; m < 2; ++m)
            #pragma unroll
            for (int r = 0; r < 4; ++r) {
                lnred[m * 16 + kb * 4 + r][wc][0] = s4[m][r];
                lnred[m * 16 + kb * 4 + r][wc][1] = ss4[m][r];
            }
    }
    __syncthreads();
    float mean[2][4], rstd[2][4];
    #pragma unroll
    for (int m = 0; m < 2; ++m)
        #pragma unroll
        for (int r = 0; r < 4; ++r) {
            int p = m * 16 + kb * 4 + r;
            float st  = lnred[p][0][0] + lnred[p][1][0] + lnred[p][2][0] + lnred[p][3][0];
            float sst = lnred[p][0][1] + lnred[p][1][1] + lnred[p][2][1] + lnred[p][3][1];
            mean[m][r] = st * (1.f / 256.f);
            float var = sst * (1.f / 256.f) - mean[m][r] * mean[m][r];
            rstd[m][r] = rsqrtf(var + 1e-6f);
        }
    #pragma unroll
    for (int n = 0; n < 4; ++n) {
        int ch = wc * 64 + n * 16 + l15;
        float gv = g[ch], bev = be[ch];
        #pragma unroll
        for (int m = 0; m < 2; ++m)
            #pragma unroll
            for (int r = 0; r < 4; ++r) {
                float y = (acc[m][n][r] - mean[m][r]) * rstd[m][r] * gv + bev;
                if (SILU) y *= sigmoidf_(y);
                int p = m * 16 + kb * 4 + r;
                Mid[p * 256 + (((ch >> 3) ^ (p & 7)) * 8) + (ch & 7)] = (bf16)y;
            }
    }
    __syncthreads();

    f32x4 acc2[2][4];
    #pragma unroll
    for (int m = 0; m < 2; ++m)
        #pragma unroll
        for (int n = 0; n < 4; ++n) acc2[m][n] = (f32x4){0.f, 0.f, 0.f, 0.f};
    cur = 0;
    #pragma unroll
    for (int ks = 0; ks < 8; ++ks) {
        if (ks < 7) stage_b(W2, &Bs[cur ^ 1][0], (ks + 1) * 32, t);
        const int ko = ((ks * 4 + kb) ^ x7) * 8;
        bf16x8 a0 = *(const bf16x8*)&Mid[a0base + ko];
        bf16x8 a1 = *(const bf16x8*)&Mid[a1base + ko];
        #pragma unroll
        for (int n = 0; n < 4; ++n) {
            bf16x8 b = *(const bf16x8*)&Bs[cur][boff[n]];
            acc2[0][n] = __builtin_amdgcn_mfma_f32_16x16x32_bf16(a0, b, acc2[0][n], 0, 0, 0);
            acc2[1][n] = __builtin_amdgcn_mfma_f32_16x16x32_bf16(a1, b, acc2[1][n], 0, 0, 0);
        }
        __syncthreads();
        cur ^= 1;
    }

    if constexpr (MODE == 0) {
        #pragma unroll
        for (int n = 0; n < 4; ++n) {
            int ch = wc * 64 + n * 16 + l15;
            float bo = b2v[ch];
            #pragma unroll
            for (int m = 0; m < 2; ++m)
                #pragma unroll
                for (int r = 0; r < 4; ++r)
                    Xf[(m * 16 + kb * 4 + r) * 256 + ch] = (bf16)(acc2[m][n][r] + bo);
        }
        __syncthreads();
        bf16* Y = (bf16*)Yv;
        const int p = t >> 3, cb = (t & 7) * 32;
        #pragma unroll
        for (int i = 0; i < 4; ++i) {
            bf16x8 v = *(const bf16x8*)&Xf[p * 256 + cb + i * 8];
            *(bf16x8*)&Y[(q0 + p) * C_ + cb + i * 8] = v;
        }
    } else {
        float* Y = (float*)Yv;
        const int bb = (int)(q0 >> 12);
        #pragma unroll
        for (int n = 0; n < 4; ++n) {
            int ch = wc * 64 + n * 16 + l15;
            float bo = b2v[ch];
            #pragma unroll
            for (int m = 0; m < 2; ++m) {
                int pp = (int)(q0 & 4095) + m * 16 + kb * 4;
                f32x4 val = {acc2[m][n][0] + bo, acc2[m][n][1] + bo,
                             acc2[m][n][2] + bo, acc2[m][n][3] + bo};
                *(f32x4*)&Y[((size_t)bb * C_ + ch) * HW + pp] = val;
            }
        }
    }
}

// ---------------------------------------------------------------- fused attn + output_proj, 512 thr (8 waves), 16 px
// LDS layout (flat, 56384 B, aliased):
//  attn: ckl@0(4160) hb@4160(2048) S@6208(7616) fxs@13824(4352) w1l@18176(6272) w2l@24448(6272) Xg@38976(8192)
//  conv: Bs0@6208(16384) Bs1@22592(16384)  [alias S/fxs/w1l/w2l, all dead]  Mid@47168(8192) lnred@55360(1024)
__global__ __launch_bounds__(512, 4) void attn_out_k(const bf16* __restrict__ px,
                                                     const bf16* __restrict__ spb,
                                                     const bf16* __restrict__ seb,
                                                     const bf16* __restrict__ w1sb,
                                                     const bf16* __restrict__ w1ckb,
                                                     const bf16* __restrict__ w2Tg,
                                                     const float* __restrict__ b1,
                                                     const float* __restrict__ b2,
                                                     const float* __restrict__ g,
                                                     const float* __restrict__ be,
                                                     const float* __restrict__ sk,
                                                     const bf16* __restrict__ wop1,
                                                     const float* __restrict__ ob1,
                                                     const float* __restrict__ og,
                                                     const float* __restrict__ obe,
                                                     const bf16* __restrict__ wop2,
                                                     const float* __restrict__ ob2,
                                                     float* __restrict__ Y)
{
    __shared__ __align__(16) char shm[56384];
    float* ckl = (float*)(shm);             // [16][65]
    float* hb  = (float*)(shm + 4160);      // [8][64]
    float* S   = (float*)(shm + 6208);      // [112][17]
    float* fxs = (float*)(shm + 13824);     // [64][17]
    bf16*  w1l = (bf16*)(shm + 18176);      // [49][64] [k][o]
    bf16*  w2l = (bf16*)(shm + 24448);      // [49][64] [k][o]
    bf16*  Bs0 = (bf16*)(shm + 6208);
    bf16*  Bs1 = (bf16*)(shm + 22592);
    bf16*  Xg  = (bf16*)(shm + 38976);      // [16][256]
    bf16*  Mid = (bf16*)(shm + 47168);      // [16][256]
    float* lnred = (float*)(shm + 55360);   // [16][8][2]

    const int t = threadIdx.x, lane = t & 63, wid = t >> 6;
    const int l15 = lane & 15, kb = lane >> 4, l31 = lane & 31;
    const int blk = blockIdx.x;
    const int batch = blk >> 8, tt = blk & 255;
    const int h0 = (tt >> 4) * 4, w0 = (tt & 15) * 4;
    const long base = (long)batch * HW;

    // hoist small per-lane params first
    const float bo  = (lane < NN) ? b1[lane] : 0.f;
    const float gl  = (lane < NN) ? g[lane] : 0.f;
    const float bel = (lane < NN) ? be[lane] : 0.f;
    const float b2l = (lane < NN) ? b2[lane] : 0.f;
    const float skv = (lane < NN) ? sk[lane] : 0.f;
    const int nn_ = (lane < NN) ? lane : 0;
    const int dy = nn_ / 7, dx = nn_ % 7;

    // stage fixup weights to LDS. Two SEQUENTIAL prefix-masked ifs (active lanes always a
    // prefix from lane 0 — global_load_lds dest is wave-uniform base + laneId*16).
    if (t < 392) GLD16(w1ckb + (size_t)t * 8, &w1l[t * 8]);
    if (t < 392) GLD16(w2Tg + (size_t)t * 8, &w2l[t * 8]);

    // ---- sim + fxsem MFMA (operands from global, L2-resident); 11 tiles over 8 waves
    const int ppy = l15 >> 2, ppx = l15 & 3;
    const long qB = base + (h0 + ppy) * 64 + (w0 + ppx);
    const bf16* bpxp = px + qB * C_ + kb * 8;
    const bf16* bsemp = seb + qB * C_ + kb * 8;

    const bool t0sim = wid < 7;      // tiles 0..6 sim; tile 7 = fxsem o 0..15
    const bool t1v = wid < 3;        // tiles 8..10 = fxsem o 16..63
    const bf16* a0p;
    {
        int u = wid * 16 + l15;
        int uy = (u * 205) >> 11, ux = u - uy * 10;
        long grow = (u < 100) ? base + refl(h0 + uy - 3) * 64 + refl(w0 + ux - 3) : base;
        a0p = t0sim ? (px + grow * C_ + kb * 8)
                    : (w1sb + (size_t)l15 * C_ + kb * 8);
    }
    const bf16* a1p = w1sb + (size_t)((wid + 1) * 16 + l15) * C_ + kb * 8;

    f32x4 acc0 = {0.f, 0.f, 0.f, 0.f}, acc1 = {0.f, 0.f, 0.f, 0.f};
    #pragma unroll
    for (int ks = 0; ks < 8; ++ks) {
        bf16x8 bp = *(const bf16x8*)(bpxp + ks * 32);
        bf16x8 bs = *(const bf16x8*)(bsemp + ks * 32);
        bf16x8 a0 = *(const bf16x8*)(a0p + ks * 32);
        acc0 = __builtin_amdgcn_mfma_f32_16x16x32_bf16(a0, t0sim ? bp : bs, acc0, 0, 0, 0);
        if (t1v) {
            bf16x8 a1 = *(const bf16x8*)(a1p + ks * 32);
            acc1 = __builtin_amdgcn_mfma_f32_16x16x32_bf16(a1, bs, acc1, 0, 0, 0);
        }
    }
    // D: row = a-row (u or o), col = pixel (l15)
    {
        float* dst = t0sim ? &S[(wid * 16 + kb * 4) * 17 + l15]
                           : &fxs[(kb * 4) * 17 + l15];
        dst[0] = acc0[0]; dst[17] = acc0[1]; dst[34] = acc0[2]; dst[51] = acc0[3];
    }
    if (t1v) {
        float* dst = &fxs[((wid + 1) * 16 + kb * 4) * 17 + l15];
        dst[0] = acc1[0]; dst[17] = acc1[1]; dst[34] = acc1[2]; dst[51] = acc1[3];
    }
    __syncthreads();   // S, fxs, w1l, w2l ready

    // ---- softmax over 49 neighbors (wave -> 2 pixels)
    #pragma unroll
    for (int j = 0; j < 2; ++j) {
        int p = wid * 2 + j, py = p >> 2, px4 = p & 3;
        int u = (py + dy) * 10 + px4 + dx;
        float sval = (lane < NN) ? S[u * 17 + p] * 0.0625f : -1e30f;
        float mx = sval;
        #pragma unroll
        for (int off = 32; off; off >>= 1) mx = fmaxf(mx, __shfl_xor(mx, off, 64));
        float ev = (lane < NN) ? __expf(sval - mx) : 0.f;
        float ssum = ev;
        #pragma unroll
        for (int off = 32; off; off >>= 1) ssum += __shfl_xor(ssum, off, 64);
        ckl[p * 65 + lane] = (lane < NN) ? (ev / ssum) * skv : 0.f;
    }

    // ---- fixup: fx = fxs + W1ck.ck + b1 -> LN49+SiLU -> conv49 -> gate -> renorm
    #pragma unroll
    for (int j = 0; j < 2; ++j) {
        int p = wid * 2 + j;
        float fxa = 0.f, fxb = 0.f;
        #pragma unroll
        for (int k = 0; k < 48; k += 2) {
            fxa += (float)w1l[k * 64 + lane] * ckl[p * 65 + k];
            fxb += (float)w1l[(k + 1) * 64 + lane] * ckl[p * 65 + k + 1];
        }
        fxa += (float)w1l[48 * 64 + lane] * ckl[p * 65 + 48];
        float fx = fxs[lane * 17 + p] + bo + fxa + fxb;
        float s = fx, ss = fx * fx;
        #pragma unroll
        for (int off = 32; off; off >>= 1) {
            s  += __shfl_xor(s, off, 64);
            ss += __shfl_xor(ss, off, 64);
        }
        float mean = s * (1.f / 49.f);
        float var  = ss * (1.f / 49.f) - mean * mean;
        float rstd = rsqrtf(var + 1e-6f);
        float hv = 0.f;
        if (lane < NN) {
            float xn = (fx - mean) * rstd * gl + bel;
            hv = xn * sigmoidf_(xn);
        }
        hb[wid * 64 + lane] = hv;
        float ckv = 0.f;
        if (lane < NN) {
            float ca = 0.f, cb = 0.f;
            #pragma unroll
            for (int k = 0; k < 48; k += 2) {
                ca += (float)w2l[k * 64 + lane] * hb[wid * 64 + k];
                cb += (float)w2l[(k + 1) * 64 + lane] * hb[wid * 64 + k + 1];
            }
            ca += (float)w2l[48 * 64 + lane] * hb[wid * 64 + 48];
            ckv = ckl[p * 65 + lane] * (1.f + sigmoidf_(b2l + ca + cb));
        }
        float tot = ckv;
        #pragma unroll
        for (int off = 32; off; off >>= 1) tot += __shfl_xor(tot, off, 64);
        ckl[p * 65 + lane] = (lane < NN) ? ckv / (tot + 1e-7f) : 0.f;
    }
    __syncthreads();   // all fixup LDS reads done -> Bs0 region (aliases S/fxs/w1l/w2l) safe to stage

    // issue W1 chunk0 staging; hides under gather
    stage_b512(wop1, Bs0, 0, t);

    // ---- gather: half-wave (32 lanes) per pixel, full 256-ch coalesced global rows -> Xg (LDS)
    {
        const int gp = wid * 2 + (lane >> 5);
        const int gpy = gp >> 2, gpx = gp & 3;
        int ry[7], rx[7];
        #pragma unroll
        for (int d = 0; d < 7; ++d) {
            ry[d] = refl(h0 + gpy + d - 3) * 64;
            rx[d] = refl(w0 + gpx + d - 3);
        }
        const bf16* pb = spb + base * C_ + l31 * 8;
        float a[8];
        #pragma unroll
        for (int e = 0; e < 8; ++e) a[e] = 0.f;
        #pragma unroll
        for (int dyy = 0; dyy < 7; ++dyy) {
            bf16x8 v[7];
            #pragma unroll
            for (int dxx = 0; dxx < 7; ++dxx)
                v[dxx] = *(const bf16x8*)(pb + (size_t)(ry[dyy] + rx[dxx]) * C_);
            #pragma unroll
            for (int dxx = 0; dxx < 7; ++dxx) {
                float cv = ckl[gp * 65 + dyy * 7 + dxx];
                #pragma unroll
                for (int e = 0; e < 8; ++e) a[e] += cv * (float)v[dxx][e];
            }
        }
        bf16x8 ov;
        #pragma unroll
        for (int e = 0; e < 8; ++e) ov[e] = (bf16)a[e];
        *(bf16x8*)&Xg[gp * 256 + ((l31 ^ (gp & 7)) * 8)] = ov;
    }
    __syncthreads();   // Xg complete + Bs0 staged (vmcnt drained)

    // ================= output_proj on the 16 gathered pixels (8 waves x 32 out-ch) =================
    const int x7 = l15 & 7;
    const int bsl = (kb ^ ((l15 >> 1) & 3)) * 8;
    int boff[2];
    #pragma unroll
    for (int n = 0; n < 2; ++n)
        boff[n] = (wid * 32 + n * 16 + l15) * 32 + bsl;

    f32x4 cacc[2];
    #pragma unroll
    for (int n = 0; n < 2; ++n) cacc[n] = (f32x4){0.f, 0.f, 0.f, 0.f};

    int cur = 0;
    #pragma unroll
    for (int ks = 0; ks < 8; ++ks) {
        if (ks < 7) stage_b512(wop1, cur ? Bs0 : Bs1, (ks + 1) * 32, t);
        const int ko = ((ks * 4 + kb) ^ x7) * 8;
        bf16x8 a = *(const bf16x8*)&Xg[l15 * 256 + ko];
        #pragma unroll
        for (int n = 0; n < 2; ++n) {
            bf16x8 b = *(const bf16x8*)&((cur ? Bs1 : Bs0)[boff[n]]);
            cacc[n] = __builtin_amdgcn_mfma_f32_16x16x32_bf16(a, b, cacc[n], 0, 0, 0);
        }
        __syncthreads();
        cur ^= 1;
    }

    stage_b512(wop2, Bs0, 0, t);   // overlap with LN phase

    // bias + per-pixel LN (pixel = kb*4+r, ch = wid*32 + n*16 + l15)
    float s4[4] = {0.f, 0.f, 0.f, 0.f}, ss4[4] = {0.f, 0.f, 0.f, 0.f};
    #pragma unroll
    for (int n = 0; n < 2; ++n) {
        float bv = ob1[wid * 32 + n * 16 + l15];
        #pragma unroll
        for (int r = 0; r < 4; ++r) {
            float v = cacc[n][r] + bv;
            cacc[n][r] = v;
            s4[r] += v; ss4[r] += v * v;
        }
    }
    #pragma unroll
    for (int off = 1; off <= 8; off <<= 1)
        #pragma unroll
        for (int r = 0; r < 4; ++r) {
            s4[r]  += __shfl_xor(s4[r], off, 64);
            ss4[r] += __shfl_xor(ss4[r], off, 64);
        }
    if (l15 == 0) {
        #pragma unroll
        for (int r = 0; r < 4; ++r) {
            lnred[((kb * 4 + r) * 8 + wid) * 2 + 0] = s4[r];
            lnred[((kb * 4 + r) * 8 + wid) * 2 + 1] = ss4[r];
        }
    }
    __syncthreads();
    float mean[4], rstd[4];
    #pragma unroll
    for (int r = 0; r < 4; ++r) {
        int p = kb * 4 + r;
        float st = 0.f, sst = 0.f;
        #pragma unroll
        for (int w = 0; w < 8; ++w) {
            st  += lnred[(p * 8 + w) * 2 + 0];
            sst += lnred[(p * 8 + w) * 2 + 1];
        }
        mean[r] = st * (1.f / 256.f);
        float var = sst * (1.f / 256.f) - mean[r] * mean[r];
        rstd[r] = rsqrtf(var + 1e-6f);
    }
    #pragma unroll
    for (int n = 0; n < 2; ++n) {
        int ch = wid * 32 + n * 16 + l15;
        float gv = og[ch], bev = obe[ch];
        #pragma unroll
        for (int r = 0; r < 4; ++r) {
            float y = (cacc[n][r] - mean[r]) * rstd[r] * gv + bev;
            int p = kb * 4 + r;
            Mid[p * 256 + (((ch >> 3) ^ (p & 7)) * 8) + (ch & 7)] = (bf16)y;
        }
    }
    __syncthreads();   // Mid + Bs0 (W2 chunk0) ready

    f32x4 cacc2[2];
    #pragma unroll
    for (int n = 0; n < 2; ++n) cacc2[n] = (f32x4){0.f, 0.f, 0.f, 0.f};
    cur = 0;
    #pragma unroll
    for (int ks = 0; ks < 8; ++ks) {
        if (ks < 7) stage_b512(wop2, cur ? Bs0 : Bs1, (ks + 1) * 32, t);
        const int ko = ((ks * 4 + kb) ^ x7) * 8;
        bf16x8 a = *(const bf16x8*)&Mid[l15 * 256 + ko];
        #pragma unroll
        for (int n = 0; n < 2; ++n) {
            bf16x8 b = *(const bf16x8*)&((cur ? Bs1 : Bs0)[boff[n]]);
            cacc2[n] = __builtin_amdgcn_mfma_f32_16x16x32_bf16(a, b, cacc2[n], 0, 0, 0);
        }
        __syncthreads();
        cur ^= 1;
    }

    // final write: fp32 channel-first; pixel p = kb*4+r -> (py=kb, pxc=r) => f32x4 over r
    {
        const size_t rowbase = ((size_t)batch * C_) * HW + (size_t)(h0 + kb) * 64 + w0;
        #pragma unroll
        for (int n = 0; n < 2; ++n) {
            int ch = wid * 32 + n * 16 + l15;
            float bv = ob2[ch];
            f32x4 val = {cacc2[n][0] + bv, cacc2[n][1] + bv, cacc2[n][2] + bv, cacc2[n][3] + bv};
            *(f32x4*)&Y[rowbase + (size_t)ch * HW] = val;
        }
    }
}

// ---------------------------------------------------------------- launch
extern "C" void kernel_launch(void* const* d_in, const int* in_sizes, int n_in,
                              void* d_out, int out_size, void* d_ws, size_t ws_size,
                              hipStream_t stream)
{
    const float* spatial  = (const float*)d_in[0];
    const float* semantic = (const float*)d_in[1];
    const float* rp_w1 = (const float*)d_in[2];
    const float* rp_b1 = (const float*)d_in[3];
    const float* rp_g  = (const float*)d_in[4];
    const float* rp_be = (const float*)d_in[5];
    const float* rp_w2 = (const float*)d_in[6];
    const float* rp_b2 = (const float*)d_in[7];
    const float* fp_w1 = (const float*)d_in[8];
    const float* fp_b1 = (const float*)d_in[9];
    const float* fp_g  = (const float*)d_in[10];
    const float* fp_be = (const float*)d_in[11];
    const float* fp_w2 = (const float*)d_in[12];
    const float* fp_b2 = (const float*)d_in[13];
    const float* op_w1 = (const float*)d_in[14];
    const float* op_b1 = (const float*)d_in[15];
    const float* op_g  = (const float*)d_in[16];
    const float* op_be = (const float*)d_in[17];
    const float* op_w2 = (const float*)d_in[18];
    const float* op_b2 = (const float*)d_in[19];
    const float* sigma = (const float*)d_in[20];

    const size_t NPX = 2 * (size_t)HW;          // 8192 pixels
    float* ws = (float*)d_ws;
    float* sk    = ws;                           // 64
    bf16* bfbase = (bf16*)(sk + 64);
    bf16* spb = bfbase;                          // [8192][256]
    bf16* seb = spb + NPX * C_;
    bf16* t1  = seb + NPX * C_;
    bf16* wrp1 = t1 + NPX * C_;
    bf16* wrp2 = wrp1 + C_ * C_;
    bf16* wop1 = wrp2 + C_ * C_;
    bf16* wop2 = wop1 + C_ * C_;
    bf16* w1sb = wop2 + C_ * C_;                 // [64][256]
    bf16* w2Tg = w1sb + 64 * C_;                 // [49][64] pad 3200
    bf16* w1ckb = w2Tg + 3200;                   // [49][64] pad 3200

    setup_k<<<4443, 256, 0, stream>>>(spatial, semantic, rp_w1, rp_w2, op_w1, op_w2,
                                      fp_w1, fp_w2, sigma,
                                      spb, seb, wrp1, wrp2, wop1, wop2,
                                      w1ckb, w1sb, w2Tg, sk);

    // range_proj fused pair: conv+bias -> LN+SiLU -> conv+bias  => t1 = px
    conv_pair<true, 0><<<256, 256, 0, stream>>>(seb, wrp1, rp_b1, rp_g, rp_be, wrp2, rp_b2, t1);

    // attn (sim MFMA + softmax + fixup + gather) fused with output_proj -> d_out
    attn_out_k<<<512, 512, 0, stream>>>(t1, spb, seb, w1sb, w1ckb, w2Tg, fp_b1, fp_b2,
                                        fp_g, fp_be, sk,
                                        wop1, op_b1, op_g, op_be, wop2, op_b2,
                                        (float*)d_out);
}

// Round 14
// 70.568 us; speedup vs baseline: 1.0003x; 1.0003x over previous
//
#include <hip/hip_runtime.h>
#include <cstdint>

#define HW 4096
#define C_ 256
#define NN 49
#define KW 305    // 49 + 256 (original fixup w1 row length)

typedef __bf16 bf16;
typedef bf16 bf16x8 __attribute__((ext_vector_type(8)));
typedef bf16 bf16x4 __attribute__((ext_vector_type(4)));
typedef float f32x4 __attribute__((ext_vector_type(4)));

#define GLD16(src, dst) __builtin_amdgcn_global_load_lds( \
    (const __attribute__((address_space(1))) uint32_t*)(src), \
    (__attribute__((address_space(3))) uint32_t*)(dst), 16, 0, 0)

__device__ __forceinline__ int refl(int i) { return i < 0 ? -i : (i > 63 ? 126 - i : i); }
__device__ __forceinline__ float sigmoidf_(float x) { return 1.f / (1.f + __expf(-x)); }

// ---------------------------------------------------------------- setup: cvtT + all weight prep, one launch
__global__ __launch_bounds__(256) void setup_k(const float* __restrict__ spatial,
                                               const float* __restrict__ semantic,
                                               const float* __restrict__ rp_w1,
                                               const float* __restrict__ rp_w2,
                                               const float* __restrict__ op_w1,
                                               const float* __restrict__ op_w2,
                                               const float* __restrict__ fp_w1,
                                               const float* __restrict__ fp_w2,
                                               const float* __restrict__ sigma,
                                               bf16* __restrict__ spb, bf16* __restrict__ seb,
                                               bf16* __restrict__ wrp1, bf16* __restrict__ wrp2,
                                               bf16* __restrict__ wop1, bf16* __restrict__ wop2,
                                               bf16* __restrict__ w1ckb, bf16* __restrict__ w1sb,
                                               bf16* __restrict__ w2Tg, float* __restrict__ sk)
{
    __shared__ float tile[32][33];
    const int bid = blockIdx.x, t = threadIdx.x;
    if (bid < 4096) {
        int z = bid >> 10, r = bid & 1023;
        int b = z & 1;
        const float* src = (z >> 1) ? semantic : spatial;
        bf16* dst = (z >> 1) ? seb : spb;
        int p0 = (r & 127) * 32, c0 = (r >> 7) * 32;
        int tx = t & 31, ty = t >> 5;
        const float* s = src + (size_t)b * C_ * HW;
        #pragma unroll
        for (int i = 0; i < 32; i += 8)
            tile[ty + i][tx] = s[(size_t)(c0 + ty + i) * HW + p0 + tx];
        __syncthreads();
        int p = t >> 3, cq = (t & 7) * 4;
        bf16x4 o = {(bf16)tile[cq][p], (bf16)tile[cq + 1][p], (bf16)tile[cq + 2][p], (bf16)tile[cq + 3][p]};
        *(bf16x4*)&dst[((size_t)b * HW + p0 + p) * C_ + c0 + cq] = o;
        return;
    }
    int pid = bid - 4096;
    if (pid < 256) {
        const float* src = (pid < 64) ? rp_w1 : (pid < 128) ? rp_w2 : (pid < 192) ? op_w1 : op_w2;
        bf16* dst = (pid < 64) ? wrp1 : (pid < 128) ? wrp2 : (pid < 192) ? wop1 : wop2;
        int i = ((pid & 63) * 256 + t) * 4;
        f32x4 v = *(const f32x4*)&src[i];
        bf16x4 o = {(bf16)v[0], (bf16)v[1], (bf16)v[2], (bf16)v[3]};
        *(bf16x4*)&dst[i] = o;
    } else if (pid == 256) {
        if (t < NN) {
            int i = t / 7, j = t % 7;
            float xg = (i - 3) * (1.f / 3.f), yg = (j - 3) * (1.f / 3.f);
            float s = sigma[0];
            sk[t] = __expf(-(xg * xg + yg * yg) / (2.f * s * s));
        }
    } else if (pid < 270) {
        int idx = (pid - 257) * 256 + t;
        if (idx < NN * 64) {
            int k = idx >> 6, o = idx & 63;
            w1ckb[idx] = (o < NN) ? (bf16)fp_w1[o * KW + k] : (bf16)0.f;
        }
    } else if (pid < 334) {
        int idx = (pid - 270) * 256 + t;
        int o = idx >> 8, c = idx & 255;
        w1sb[idx] = (o < NN) ? (bf16)fp_w1[o * KW + NN + c] : (bf16)0.f;
    } else {
        int idx = (pid - 334) * 256 + t;
        if (idx < NN * 64) {
            int k = idx >> 6, o = idx & 63;
            w2Tg[idx] = (o < NN) ? (bf16)fp_w2[o * NN + k] : (bf16)0.f;
        }
    }
}

// ---------------------------------------------------------------- B-chunk staging (256 threads): 256 out x 32 k
__device__ __forceinline__ void stage_b(const bf16* __restrict__ Wp, bf16* dst, int kc, int t)
{
    const bf16* gB = Wp + (size_t)(t >> 2) * C_ + kc + (((t & 3) ^ ((t >> 3) & 3)) * 8);
    #pragma unroll
    for (int ii = 0; ii < 4; ++ii)
        GLD16(gB + (size_t)ii * 64 * C_, dst + ii * 2048 + t * 8);
}

// ---------------------------------------------------------------- B-chunk staging (512 threads): 256 out x 32 k
// each GLD16 round covers 512 thr x 8 bf16 = 4096 elements (rows 0..127, then 128..255)
__device__ __forceinline__ void stage_b512(const bf16* __restrict__ Wp, bf16* dst, int kc, int t)
{
    const bf16* gB = Wp + (size_t)(t >> 2) * C_ + kc + (((t & 3) ^ ((t >> 3) & 3)) * 8);
    GLD16(gB, dst + t * 8);
    GLD16(gB + (size_t)128 * C_, dst + 4096 + t * 8);
}

// ---------------------------------------------------------------- fused conv1x1 -> LN(+SiLU) -> conv1x1, 32 px/block
template<bool SILU, int MODE>
__global__ __launch_bounds__(256) void conv_pair(const bf16* __restrict__ X,
                                                 const bf16* __restrict__ W1,
                                                 const float* __restrict__ b1v,
                                                 const float* __restrict__ g,
                                                 const float* __restrict__ be,
                                                 const bf16* __restrict__ W2,
                                                 const float* __restrict__ b2v,
                                                 void* __restrict__ Yv)
{
    __shared__ __align__(16) bf16 Xf[32 * 256];
    __shared__ __align__(16) bf16 Mid[32 * 256];
    __shared__ __align__(16) bf16 Bs[2][256 * 32];
    __shared__ float lnred[32][4][2];
    const int t = threadIdx.x;
    const int lane = t & 63, wc = t >> 6;
    const int l15 = lane & 15, kb = lane >> 4;
    const long q0 = (long)blockIdx.x * 32;

    {
        const int r8 = t >> 5, slot = t & 31;
        const bf16* gX = X + (q0 + r8) * C_ + ((slot ^ (r8 & 7)) * 8);
        #pragma unroll
        for (int i = 0; i < 4; ++i)
            GLD16(gX + (size_t)i * 8 * C_, &Xf[i * 2048 + t * 8]);
    }
    stage_b(W1, &Bs[0][0], 0, t);

    const int x7 = l15 & 7;
    const int bsl = (kb ^ ((l15 >> 1) & 3)) * 8;
    int boff[4];
    #pragma unroll
    for (int n = 0; n < 4; ++n)
        boff[n] = (wc * 64 + n * 16 + l15) * 32 + bsl;
    const int a0base = l15 * 256;
    const int a1base = (16 + l15) * 256;

    f32x4 acc[2][4];
    #pragma unroll
    for (int m = 0; m < 2; ++m)
        #pragma unroll
        for (int n = 0; n < 4; ++n) acc[m][n] = (f32x4){0.f, 0.f, 0.f, 0.f};

    __syncthreads();
    int cur = 0;
    #pragma unroll
    for (int ks = 0; ks < 8; ++ks) {
        if (ks < 7) stage_b(W1, &Bs[cur ^ 1][0], (ks + 1) * 32, t);
        const int ko = ((ks * 4 + kb) ^ x7) * 8;
        bf16x8 a0 = *(const bf16x8*)&Xf[a0base + ko];
        bf16x8 a1 = *(const bf16x8*)&Xf[a1base + ko];
        #pragma unroll
        for (int n = 0; n < 4; ++n) {
            bf16x8 b = *(const bf16x8*)&Bs[cur][boff[n]];
            acc[0][n] = __builtin_amdgcn_mfma_f32_16x16x32_bf16(a0, b, acc[0][n], 0, 0, 0);
            acc[1][n] = __builtin_amdgcn_mfma_f32_16x16x32_bf16(a1, b, acc[1][n], 0, 0, 0);
        }
        __syncthreads();
        cur ^= 1;
    }

    stage_b(W2, &Bs[0][0], 0, t);

    float s4[2][4], ss4[2][4];
    #pragma unroll
    for (int m = 0; m < 2; ++m)
        #pragma unroll
        for (int r = 0; r < 4; ++r) { s4[m][r] = 0.f; ss4[m][r] = 0.f; }
    #pragma unroll
    for (int n = 0; n < 4; ++n) {
        float bo = b1v[wc * 64 + n * 16 + l15];
        #pragma unroll
        for (int m = 0; m < 2; ++m)
            #pragma unroll
            for (int r = 0; r < 4; ++r) {
                float v = acc[m][n][r] + bo;
                acc[m][n][r] = v;
                s4[m][r] += v; ss4[m][r] += v * v;
            }
    }
    #pragma unroll
    for (int off = 1; off <= 8; off <<= 1)
        #pragma unroll
        for (int m = 0; m < 2; ++m)
            #pragma unroll
            for (int r = 0; r < 4; ++r) {
                s4[m][r]  += __shfl_xor(s4[m][r], off, 64);
                ss4[m][r] += __shfl_xor(ss4[m][r], off, 64);
            }
    if (l15 == 0) {
        #pragma unroll
        for (int m = 0; m < 2; ++m)
            #pragma unroll
            for (int r = 0; r < 4; ++r) {
                lnred[m * 16 + kb * 4 + r][wc][0] = s4[m][r];
                lnred[m * 16 + kb * 4 + r][wc][1] = ss4[m][r];
            }
    }
    __syncthreads();
    float mean[2][4], rstd[2][4];
    #pragma unroll
    for (int m = 0; m < 2; ++m)
        #pragma unroll
        for (int r = 0; r < 4; ++r) {
            int p = m * 16 + kb * 4 + r;
            float st  = lnred[p][0][0] + lnred[p][1][0] + lnred[p][2][0] + lnred[p][3][0];
            float sst = lnred[p][0][1] + lnred[p][1][1] + lnred[p][2][1] + lnred[p][3][1];
            mean[m][r] = st * (1.f / 256.f);
            float var = sst * (1.f / 256.f) - mean[m][r] * mean[m][r];
            rstd[m][r] = rsqrtf(var + 1e-6f);
        }
    #pragma unroll
    for (int n = 0; n < 4; ++n) {
        int ch = wc * 64 + n * 16 + l15;
        float gv = g[ch], bev = be[ch];
        #pragma unroll
        for (int m = 0; m < 2; ++m)
            #pragma unroll
            for (int r = 0; r < 4; ++r) {
                float y = (acc[m][n][r] - mean[m][r]) * rstd[m][r] * gv + bev;
                if (SILU) y *= sigmoidf_(y);
                int p = m * 16 + kb * 4 + r;
                Mid[p * 256 + (((ch >> 3) ^ (p & 7)) * 8) + (ch & 7)] = (bf16)y;
            }
    }
    __syncthreads();

    f32x4 acc2[2][4];
    #pragma unroll
    for (int m = 0; m < 2; ++m)
        #pragma unroll
        for (int n = 0; n < 4; ++n) acc2[m][n] = (f32x4){0.f, 0.f, 0.f, 0.f};
    cur = 0;
    #pragma unroll
    for (int ks = 0; ks < 8; ++ks) {
        if (ks < 7) stage_b(W2, &Bs[cur ^ 1][0], (ks + 1) * 32, t);
        const int ko = ((ks * 4 + kb) ^ x7) * 8;
        bf16x8 a0 = *(const bf16x8*)&Mid[a0base + ko];
        bf16x8 a1 = *(const bf16x8*)&Mid[a1base + ko];
        #pragma unroll
        for (int n = 0; n < 4; ++n) {
            bf16x8 b = *(const bf16x8*)&Bs[cur][boff[n]];
            acc2[0][n] = __builtin_amdgcn_mfma_f32_16x16x32_bf16(a0, b, acc2[0][n], 0, 0, 0);
            acc2[1][n] = __builtin_amdgcn_mfma_f32_16x16x32_bf16(a1, b, acc2[1][n], 0, 0, 0);
        }
        __syncthreads();
        cur ^= 1;
    }

    if constexpr (MODE == 0) {
        #pragma unroll
        for (int n = 0; n < 4; ++n) {
            int ch = wc * 64 + n * 16 + l15;
            float bo = b2v[ch];
            #pragma unroll
            for (int m = 0; m < 2; ++m)
                #pragma unroll
                for (int r = 0; r < 4; ++r)
                    Xf[(m * 16 + kb * 4 + r) * 256 + ch] = (bf16)(acc2[m][n][r] + bo);
        }
        __syncthreads();
        bf16* Y = (bf16*)Yv;
        const int p = t >> 3, cb = (t & 7) * 32;
        #pragma unroll
        for (int i = 0; i < 4; ++i) {
            bf16x8 v = *(const bf16x8*)&Xf[p * 256 + cb + i * 8];
            *(bf16x8*)&Y[(q0 + p) * C_ + cb + i * 8] = v;
        }
    } else {
        float* Y = (float*)Yv;
        const int bb = (int)(q0 >> 12);
        #pragma unroll
        for (int n = 0; n < 4; ++n) {
            int ch = wc * 64 + n * 16 + l15;
            float bo = b2v[ch];
            #pragma unroll
            for (int m = 0; m < 2; ++m) {
                int pp = (int)(q0 & 4095) + m * 16 + kb * 4;
                f32x4 val = {acc2[m][n][0] + bo, acc2[m][n][1] + bo,
                             acc2[m][n][2] + bo, acc2[m][n][3] + bo};
                *(f32x4*)&Y[((size_t)bb * C_ + ch) * HW + pp] = val;
            }
        }
    }
}

// ---------------------------------------------------------------- fused attn + output_proj, 512 thr (8 waves), 16 px
// LDS layout (flat, 56384 B, aliased):
//  attn: ckl@0(4160) hb@4160(2048) S@6208(7616) fxs@13824(4352) w1l@18176(6272) w2l@24448(6272) Xg@38976(8192)
//  conv: Bs0@6208(16384) Bs1@22592(16384)  [alias S/fxs/w1l/w2l, all dead]  Mid@47168(8192) lnred@55360(1024)
// launch_bounds (512, 2): allow up to 256 VGPR — R13's (512,4) capped at 64 and killed MLP.
__global__ __launch_bounds__(512, 2) void attn_out_k(const bf16* __restrict__ px,
                                                     const bf16* __restrict__ spb,
                                                     const bf16* __restrict__ seb,
                                                     const bf16* __restrict__ w1sb,
                                                     const bf16* __restrict__ w1ckb,
                                                     const bf16* __restrict__ w2Tg,
                                                     const float* __restrict__ b1,
                                                     const float* __restrict__ b2,
                                                     const float* __restrict__ g,
                                                     const float* __restrict__ be,
                                                     const float* __restrict__ sk,
                                                     const bf16* __restrict__ wop1,
                                                     const float* __restrict__ ob1,
                                                     const float* __restrict__ og,
                                                     const float* __restrict__ obe,
                                                     const bf16* __restrict__ wop2,
                                                     const float* __restrict__ ob2,
                                                     float* __restrict__ Y)
{
    __shared__ __align__(16) char shm[56384];
    float* ckl = (float*)(shm);             // [16][65]
    float* hb  = (float*)(shm + 4160);      // [8][64]
    float* S   = (float*)(shm + 6208);      // [112][17]
    float* fxs = (float*)(shm + 13824);     // [64][17]
    bf16*  w1l = (bf16*)(shm + 18176);      // [49][64] [k][o]
    bf16*  w2l = (bf16*)(shm + 24448);      // [49][64] [k][o]
    bf16*  Bs0 = (bf16*)(shm + 6208);
    bf16*  Bs1 = (bf16*)(shm + 22592);
    bf16*  Xg  = (bf16*)(shm + 38976);      // [16][256]
    bf16*  Mid = (bf16*)(shm + 47168);      // [16][256]
    float* lnred = (float*)(shm + 55360);   // [16][8][2]

    const int t = threadIdx.x, lane = t & 63, wid = t >> 6;
    const int l15 = lane & 15, kb = lane >> 4, l31 = lane & 31;
    const int blk = blockIdx.x;
    const int batch = blk >> 8, tt = blk & 255;
    const int h0 = (tt >> 4) * 4, w0 = (tt & 15) * 4;
    const long base = (long)batch * HW;

    // hoist small per-lane params first
    const float bo  = (lane < NN) ? b1[lane] : 0.f;
    const float gl  = (lane < NN) ? g[lane] : 0.f;
    const float bel = (lane < NN) ? be[lane] : 0.f;
    const float b2l = (lane < NN) ? b2[lane] : 0.f;
    const float skv = (lane < NN) ? sk[lane] : 0.f;
    const int nn_ = (lane < NN) ? lane : 0;
    const int dy = nn_ / 7, dx = nn_ % 7;

    // stage fixup weights to LDS. Two SEQUENTIAL prefix-masked ifs (active lanes always a
    // prefix from lane 0 — global_load_lds dest is wave-uniform base + laneId*16).
    if (t < 392) GLD16(w1ckb + (size_t)t * 8, &w1l[t * 8]);
    if (t < 392) GLD16(w2Tg + (size_t)t * 8, &w2l[t * 8]);

    // ---- sim + fxsem MFMA (operands from global, L2-resident); 11 tiles over 8 waves
    const int ppy = l15 >> 2, ppx = l15 & 3;
    const long qB = base + (h0 + ppy) * 64 + (w0 + ppx);
    const bf16* bpxp = px + qB * C_ + kb * 8;
    const bf16* bsemp = seb + qB * C_ + kb * 8;

    const bool t0sim = wid < 7;      // tiles 0..6 sim; tile 7 = fxsem o 0..15
    const bool t1v = wid < 3;        // tiles 8..10 = fxsem o 16..63
    const bf16* a0p;
    {
        int u = wid * 16 + l15;
        int uy = (u * 205) >> 11, ux = u - uy * 10;
        long grow = (u < 100) ? base + refl(h0 + uy - 3) * 64 + refl(w0 + ux - 3) : base;
        a0p = t0sim ? (px + grow * C_ + kb * 8)
                    : (w1sb + (size_t)l15 * C_ + kb * 8);
    }
    const bf16* a1p = w1sb + (size_t)((wid + 1) * 16 + l15) * C_ + kb * 8;

    f32x4 acc0 = {0.f, 0.f, 0.f, 0.f}, acc1 = {0.f, 0.f, 0.f, 0.f};
    #pragma unroll
    for (int ks = 0; ks < 8; ++ks) {
        bf16x8 bp = *(const bf16x8*)(bpxp + ks * 32);
        bf16x8 bs = *(const bf16x8*)(bsemp + ks * 32);
        bf16x8 a0 = *(const bf16x8*)(a0p + ks * 32);
        acc0 = __builtin_amdgcn_mfma_f32_16x16x32_bf16(a0, t0sim ? bp : bs, acc0, 0, 0, 0);
        if (t1v) {
            bf16x8 a1 = *(const bf16x8*)(a1p + ks * 32);
            acc1 = __builtin_amdgcn_mfma_f32_16x16x32_bf16(a1, bs, acc1, 0, 0, 0);
        }
    }
    // D: row = a-row (u or o), col = pixel (l15)
    {
        float* dst = t0sim ? &S[(wid * 16 + kb * 4) * 17 + l15]
                           : &fxs[(kb * 4) * 17 + l15];
        dst[0] = acc0[0]; dst[17] = acc0[1]; dst[34] = acc0[2]; dst[51] = acc0[3];
    }
    if (t1v) {
        float* dst = &fxs[((wid + 1) * 16 + kb * 4) * 17 + l15];
        dst[0] = acc1[0]; dst[17] = acc1[1]; dst[34] = acc1[2]; dst[51] = acc1[3];
    }
    __syncthreads();   // S, fxs, w1l, w2l ready

    // ---- softmax over 49 neighbors (wave -> 2 pixels)
    #pragma unroll
    for (int j = 0; j < 2; ++j) {
        int p = wid * 2 + j, py = p >> 2, px4 = p & 3;
        int u = (py + dy) * 10 + px4 + dx;
        float sval = (lane < NN) ? S[u * 17 + p] * 0.0625f : -1e30f;
        float mx = sval;
        #pragma unroll
        for (int off = 32; off; off >>= 1) mx = fmaxf(mx, __shfl_xor(mx, off, 64));
        float ev = (lane < NN) ? __expf(sval - mx) : 0.f;
        float ssum = ev;
        #pragma unroll
        for (int off = 32; off; off >>= 1) ssum += __shfl_xor(ssum, off, 64);
        ckl[p * 65 + lane] = (lane < NN) ? (ev / ssum) * skv : 0.f;
    }

    // ---- fixup: fx = fxs + W1ck.ck + b1 -> LN49+SiLU -> conv49 -> gate -> renorm
    #pragma unroll
    for (int j = 0; j < 2; ++j) {
        int p = wid * 2 + j;
        float fxa = 0.f, fxb = 0.f;
        #pragma unroll
        for (int k = 0; k < 48; k += 2) {
            fxa += (float)w1l[k * 64 + lane] * ckl[p * 65 + k];
            fxb += (float)w1l[(k + 1) * 64 + lane] * ckl[p * 65 + k + 1];
        }
        fxa += (float)w1l[48 * 64 + lane] * ckl[p * 65 + 48];
        float fx = fxs[lane * 17 + p] + bo + fxa + fxb;
        float s = fx, ss = fx * fx;
        #pragma unroll
        for (int off = 32; off; off >>= 1) {
            s  += __shfl_xor(s, off, 64);
            ss += __shfl_xor(ss, off, 64);
        }
        float mean = s * (1.f / 49.f);
        float var  = ss * (1.f / 49.f) - mean * mean;
        float rstd = rsqrtf(var + 1e-6f);
        float hv = 0.f;
        if (lane < NN) {
            float xn = (fx - mean) * rstd * gl + bel;
            hv = xn * sigmoidf_(xn);
        }
        hb[wid * 64 + lane] = hv;
        float ckv = 0.f;
        if (lane < NN) {
            float ca = 0.f, cb = 0.f;
            #pragma unroll
            for (int k = 0; k < 48; k += 2) {
                ca += (float)w2l[k * 64 + lane] * hb[wid * 64 + k];
                cb += (float)w2l[(k + 1) * 64 + lane] * hb[wid * 64 + k + 1];
            }
            ca += (float)w2l[48 * 64 + lane] * hb[wid * 64 + 48];
            ckv = ckl[p * 65 + lane] * (1.f + sigmoidf_(b2l + ca + cb));
        }
        float tot = ckv;
        #pragma unroll
        for (int off = 32; off; off >>= 1) tot += __shfl_xor(tot, off, 64);
        ckl[p * 65 + lane] = (lane < NN) ? ckv / (tot + 1e-7f) : 0.f;
    }
    __syncthreads();   // all fixup LDS reads done -> Bs0 region (aliases S/fxs/w1l/w2l) safe to stage

    // issue W1 chunk0 staging; hides under gather
    stage_b512(wop1, Bs0, 0, t);

    // ---- gather: half-wave (32 lanes) per pixel, full 256-ch coalesced global rows -> Xg (LDS)
    {
        const int gp = wid * 2 + (lane >> 5);
        const int gpy = gp >> 2, gpx = gp & 3;
        int ry[7], rx[7];
        #pragma unroll
        for (int d = 0; d < 7; ++d) {
            ry[d] = refl(h0 + gpy + d - 3) * 64;
            rx[d] = refl(w0 + gpx + d - 3);
        }
        const bf16* pb = spb + base * C_ + l31 * 8;
        float a[8];
        #pragma unroll
        for (int e = 0; e < 8; ++e) a[e] = 0.f;
        #pragma unroll
        for (int dyy = 0; dyy < 7; ++dyy) {
            bf16x8 v[7];
            #pragma unroll
            for (int dxx = 0; dxx < 7; ++dxx)
                v[dxx] = *(const bf16x8*)(pb + (size_t)(ry[dyy] + rx[dxx]) * C_);
            #pragma unroll
            for (int dxx = 0; dxx < 7; ++dxx) {
                float cv = ckl[gp * 65 + dyy * 7 + dxx];
                #pragma unroll
                for (int e = 0; e < 8; ++e) a[e] += cv * (float)v[dxx][e];
            }
        }
        bf16x8 ov;
        #pragma unroll
        for (int e = 0; e < 8; ++e) ov[e] = (bf16)a[e];
        *(bf16x8*)&Xg[gp * 256 + ((l31 ^ (gp & 7)) * 8)] = ov;
    }
    __syncthreads();   // Xg complete + Bs0 staged (vmcnt drained)

    // ================= output_proj on the 16 gathered pixels (8 waves x 32 out-ch) =================
    const int x7 = l15 & 7;
    const int bsl = (kb ^ ((l15 >> 1) & 3)) * 8;
    int boff[2];
    #pragma unroll
    for (int n = 0; n < 2; ++n)
        boff[n] = (wid * 32 + n * 16 + l15) * 32 + bsl;

    f32x4 cacc[2];
    #pragma unroll
    for (int n = 0; n < 2; ++n) cacc[n] = (f32x4){0.f, 0.f, 0.f, 0.f};

    int cur = 0;
    #pragma unroll
    for (int ks = 0; ks < 8; ++ks) {
        if (ks < 7) stage_b512(wop1, cur ? Bs0 : Bs1, (ks + 1) * 32, t);
        const int ko = ((ks * 4 + kb) ^ x7) * 8;
        bf16x8 a = *(const bf16x8*)&Xg[l15 * 256 + ko];
        #pragma unroll
        for (int n = 0; n < 2; ++n) {
            bf16x8 b = *(const bf16x8*)&((cur ? Bs1 : Bs0)[boff[n]]);
            cacc[n] = __builtin_amdgcn_mfma_f32_16x16x32_bf16(a, b, cacc[n], 0, 0, 0);
        }
        __syncthreads();
        cur ^= 1;
    }

    stage_b512(wop2, Bs0, 0, t);   // overlap with LN phase

    // bias + per-pixel LN (pixel = kb*4+r, ch = wid*32 + n*16 + l15)
    float s4[4] = {0.f, 0.f, 0.f, 0.f}, ss4[4] = {0.f, 0.f, 0.f, 0.f};
    #pragma unroll
    for (int n = 0; n < 2; ++n) {
        float bv = ob1[wid * 32 + n * 16 + l15];
        #pragma unroll
        for (int r = 0; r < 4; ++r) {
            float v = cacc[n][r] + bv;
            cacc[n][r] = v;
            s4[r] += v; ss4[r] += v * v;
        }
    }
    #pragma unroll
    for (int off = 1; off <= 8; off <<= 1)
        #pragma unroll
        for (int r = 0; r < 4; ++r) {
            s4[r]  += __shfl_xor(s4[r], off, 64);
            ss4[r] += __shfl_xor(ss4[r], off, 64);
        }
    if (l15 == 0) {
        #pragma unroll
        for (int r = 0; r < 4; ++r) {
            lnred[((kb * 4 + r) * 8 + wid) * 2 + 0] = s4[r];
            lnred[((kb * 4 + r) * 8 + wid) * 2 + 1] = ss4[r];
        }
    }
    __syncthreads();
    float mean[4], rstd[4];
    #pragma unroll
    for (int r = 0; r < 4; ++r) {
        int p = kb * 4 + r;
        float st = 0.f, sst = 0.f;
        #pragma unroll
        for (int w = 0; w < 8; ++w) {
            st  += lnred[(p * 8 + w) * 2 + 0];
            sst += lnred[(p * 8 + w) * 2 + 1];
        }
        mean[r] = st * (1.f / 256.f);
        float var = sst * (1.f / 256.f) - mean[r] * mean[r];
        rstd[r] = rsqrtf(var + 1e-6f);
    }
    #pragma unroll
    for (int n = 0; n < 2; ++n) {
        int ch = wid * 32 + n * 16 + l15;
        float gv = og[ch], bev = obe[ch];
        #pragma unroll
        for (int r = 0; r < 4; ++r) {
            float y = (cacc[n][r] - mean[r]) * rstd[r] * gv + bev;
            int p = kb * 4 + r;
            Mid[p * 256 + (((ch >> 3) ^ (p & 7)) * 8) + (ch & 7)] = (bf16)y;
        }
    }
    __syncthreads();   // Mid + Bs0 (W2 chunk0) ready

    f32x4 cacc2[2];
    #pragma unroll
    for (int n = 0; n < 2; ++n) cacc2[n] = (f32x4){0.f, 0.f, 0.f, 0.f};
    cur = 0;
    #pragma unroll
    for (int ks = 0; ks < 8; ++ks) {
        if (ks < 7) stage_b512(wop2, cur ? Bs0 : Bs1, (ks + 1) * 32, t);
        const int ko = ((ks * 4 + kb) ^ x7) * 8;
        bf16x8 a = *(const bf16x8*)&Mid[l15 * 256 + ko];
        #pragma unroll
        for (int n = 0; n < 2; ++n) {
            bf16x8 b = *(const bf16x8*)&((cur ? Bs1 : Bs0)[boff[n]]);
            cacc2[n] = __builtin_amdgcn_mfma_f32_16x16x32_bf16(a, b, cacc2[n], 0, 0, 0);
        }
        __syncthreads();
        cur ^= 1;
    }

    // final write: fp32 channel-first; pixel p = kb*4+r -> (py=kb, pxc=r) => f32x4 over r
    {
        const size_t rowbase = ((size_t)batch * C_) * HW + (size_t)(h0 + kb) * 64 + w0;
        #pragma unroll
        for (int n = 0; n < 2; ++n) {
            int ch = wid * 32 + n * 16 + l15;
            float bv = ob2[ch];
            f32x4 val = {cacc2[n][0] + bv, cacc2[n][1] + bv, cacc2[n][2] + bv, cacc2[n][3] + bv};
            *(f32x4*)&Y[rowbase + (size_t)ch * HW] = val;
        }
    }
}

// ---------------------------------------------------------------- launch
extern "C" void kernel_launch(void* const* d_in, const int* in_sizes, int n_in,
                              void* d_out, int out_size, void* d_ws, size_t ws_size,
                              hipStream_t stream)
{
    const float* spatial  = (const float*)d_in[0];
    const float* semantic = (const float*)d_in[1];
    const float* rp_w1 = (const float*)d_in[2];
    const float* rp_b1 = (const float*)d_in[3];
    const float* rp_g  = (const float*)d_in[4];
    const float* rp_be = (const float*)d_in[5];
    const float* rp_w2 = (const float*)d_in[6];
    const float* rp_b2 = (const float*)d_in[7];
    const float* fp_w1 = (const float*)d_in[8];
    const float* fp_b1 = (const float*)d_in[9];
    const float* fp_g  = (const float*)d_in[10];
    const float* fp_be = (const float*)d_in[11];
    const float* fp_w2 = (const float*)d_in[12];
    const float* fp_b2 = (const float*)d_in[13];
    const float* op_w1 = (const float*)d_in[14];
    const float* op_b1 = (const float*)d_in[15];
    const float* op_g  = (const float*)d_in[16];
    const float* op_be = (const float*)d_in[17];
    const float* op_w2 = (const float*)d_in[18];
    const float* op_b2 = (const float*)d_in[19];
    const float* sigma = (const float*)d_in[20];

    const size_t NPX = 2 * (size_t)HW;          // 8192 pixels
    float* ws = (float*)d_ws;
    float* sk    = ws;                           // 64
    bf16* bfbase = (bf16*)(sk + 64);
    bf16* spb = bfbase;                          // [8192][256]
    bf16* seb = spb + NPX * C_;
    bf16* t1  = seb + NPX * C_;
    bf16* wrp1 = t1 + NPX * C_;
    bf16* wrp2 = wrp1 + C_ * C_;
    bf16* wop1 = wrp2 + C_ * C_;
    bf16* wop2 = wop1 + C_ * C_;
    bf16* w1sb = wop2 + C_ * C_;                 // [64][256]
    bf16* w2Tg = w1sb + 64 * C_;                 // [49][64] pad 3200
    bf16* w1ckb = w2Tg + 3200;                   // [49][64] pad 3200

    setup_k<<<4443, 256, 0, stream>>>(spatial, semantic, rp_w1, rp_w2, op_w1, op_w2,
                                      fp_w1, fp_w2, sigma,
                                      spb, seb, wrp1, wrp2, wop1, wop2,
                                      w1ckb, w1sb, w2Tg, sk);

    // range_proj fused pair: conv+bias -> LN+SiLU -> conv+bias  => t1 = px
    conv_pair<true, 0><<<256, 256, 0, stream>>>(seb, wrp1, rp_b1, rp_g, rp_be, wrp2, rp_b2, t1);

    // attn (sim MFMA + softmax + fixup + gather) fused with output_proj -> d_out
    attn_out_k<<<512, 512, 0, stream>>>(t1, spb, seb, w1sb, w1ckb, w2Tg, fp_b1, fp_b2,
                                        fp_g, fp_be, sk,
                                        wop1, op_b1, op_g, op_be, wop2, op_b2,
                                        (float*)d_out);
}

// Round 15
// 64.843 us; speedup vs baseline: 1.0886x; 1.0883x over previous
//
#include <hip/hip_runtime.h>
#include <cstdint>

#define HW 4096
#define C_ 256
#define NN 49
#define KW 305    // 49 + 256 (original fixup w1 row length)

typedef __bf16 bf16;
typedef bf16 bf16x8 __attribute__((ext_vector_type(8)));
typedef bf16 bf16x4 __attribute__((ext_vector_type(4)));
typedef float f32x4 __attribute__((ext_vector_type(4)));

#define GLD16(src, dst) __builtin_amdgcn_global_load_lds( \
    (const __attribute__((address_space(1))) uint32_t*)(src), \
    (__attribute__((address_space(3))) uint32_t*)(dst), 16, 0, 0)

__device__ __forceinline__ int refl(int i) { return i < 0 ? -i : (i > 63 ? 126 - i : i); }
__device__ __forceinline__ float sigmoidf_(float x) { return 1.f / (1.f + __expf(-x)); }

// ---------------------------------------------------------------- setup: cvtT + all weight prep, one launch
__global__ __launch_bounds__(256) void setup_k(const float* __restrict__ spatial,
                                               const float* __restrict__ semantic,
                                               const float* __restrict__ rp_w1,
                                               const float* __restrict__ rp_w2,
                                               const float* __restrict__ op_w1,
                                               const float* __restrict__ op_w2,
                                               const float* __restrict__ fp_w1,
                                               const float* __restrict__ fp_w2,
                                               const float* __restrict__ sigma,
                                               bf16* __restrict__ spb, bf16* __restrict__ seb,
                                               bf16* __restrict__ wrp1, bf16* __restrict__ wrp2,
                                               bf16* __restrict__ wop1, bf16* __restrict__ wop2,
                                               bf16* __restrict__ w1ckb, bf16* __restrict__ w1sb,
                                               bf16* __restrict__ w2Tg, float* __restrict__ sk)
{
    __shared__ float tile[32][33];
    const int bid = blockIdx.x, t = threadIdx.x;
    if (bid < 4096) {
        int z = bid >> 10, r = bid & 1023;
        int b = z & 1;
        const float* src = (z >> 1) ? semantic : spatial;
        bf16* dst = (z >> 1) ? seb : spb;
        int p0 = (r & 127) * 32, c0 = (r >> 7) * 32;
        int tx = t & 31, ty = t >> 5;
        const float* s = src + (size_t)b * C_ * HW;
        #pragma unroll
        for (int i = 0; i < 32; i += 8)
            tile[ty + i][tx] = s[(size_t)(c0 + ty + i) * HW + p0 + tx];
        __syncthreads();
        int p = t >> 3, cq = (t & 7) * 4;
        bf16x4 o = {(bf16)tile[cq][p], (bf16)tile[cq + 1][p], (bf16)tile[cq + 2][p], (bf16)tile[cq + 3][p]};
        *(bf16x4*)&dst[((size_t)b * HW + p0 + p) * C_ + c0 + cq] = o;
        return;
    }
    int pid = bid - 4096;
    if (pid < 256) {
        const float* src = (pid < 64) ? rp_w1 : (pid < 128) ? rp_w2 : (pid < 192) ? op_w1 : op_w2;
        bf16* dst = (pid < 64) ? wrp1 : (pid < 128) ? wrp2 : (pid < 192) ? wop1 : wop2;
        int i = ((pid & 63) * 256 + t) * 4;
        f32x4 v = *(const f32x4*)&src[i];
        bf16x4 o = {(bf16)v[0], (bf16)v[1], (bf16)v[2], (bf16)v[3]};
        *(bf16x4*)&dst[i] = o;
    } else if (pid == 256) {
        if (t < NN) {
            int i = t / 7, j = t % 7;
            float xg = (i - 3) * (1.f / 3.f), yg = (j - 3) * (1.f / 3.f);
            float s = sigma[0];
            sk[t] = __expf(-(xg * xg + yg * yg) / (2.f * s * s));
        }
    } else if (pid < 270) {
        int idx = (pid - 257) * 256 + t;
        if (idx < NN * 64) {
            int k = idx >> 6, o = idx & 63;
            w1ckb[idx] = (o < NN) ? (bf16)fp_w1[o * KW + k] : (bf16)0.f;
        }
    } else if (pid < 334) {
        int idx = (pid - 270) * 256 + t;
        int o = idx >> 8, c = idx & 255;
        w1sb[idx] = (o < NN) ? (bf16)fp_w1[o * KW + NN + c] : (bf16)0.f;
    } else {
        int idx = (pid - 334) * 256 + t;
        if (idx < NN * 64) {
            int k = idx >> 6, o = idx & 63;
            w2Tg[idx] = (o < NN) ? (bf16)fp_w2[o * NN + k] : (bf16)0.f;
        }
    }
}

// ---------------------------------------------------------------- B-chunk staging (256 threads): 256 out x 32 k
__device__ __forceinline__ void stage_b(const bf16* __restrict__ Wp, bf16* dst, int kc, int t)
{
    const bf16* gB = Wp + (size_t)(t >> 2) * C_ + kc + (((t & 3) ^ ((t >> 3) & 3)) * 8);
    #pragma unroll
    for (int ii = 0; ii < 4; ++ii)
        GLD16(gB + (size_t)ii * 64 * C_, dst + ii * 2048 + t * 8);
}

// ---------------------------------------------------------------- fused conv1x1 -> LN(+SiLU) -> conv1x1, 32 px/block
template<bool SILU, int MODE>
__global__ __launch_bounds__(256) void conv_pair(const bf16* __restrict__ X,
                                                 const bf16* __restrict__ W1,
                                                 const float* __restrict__ b1v,
                                                 const float* __restrict__ g,
                                                 const float* __restrict__ be,
                                                 const bf16* __restrict__ W2,
                                                 const float* __restrict__ b2v,
                                                 void* __restrict__ Yv)
{
    __shared__ __align__(16) bf16 Xf[32 * 256];
    __shared__ __align__(16) bf16 Mid[32 * 256];
    __shared__ __align__(16) bf16 Bs[2][256 * 32];
    __shared__ float lnred[32][4][2];
    const int t = threadIdx.x;
    const int lane = t & 63, wc = t >> 6;
    const int l15 = lane & 15, kb = lane >> 4;
    const long q0 = (long)blockIdx.x * 32;

    {
        const int r8 = t >> 5, slot = t & 31;
        const bf16* gX = X + (q0 + r8) * C_ + ((slot ^ (r8 & 7)) * 8);
        #pragma unroll
        for (int i = 0; i < 4; ++i)
            GLD16(gX + (size_t)i * 8 * C_, &Xf[i * 2048 + t * 8]);
    }
    stage_b(W1, &Bs[0][0], 0, t);

    const int x7 = l15 & 7;
    const int bsl = (kb ^ ((l15 >> 1) & 3)) * 8;
    int boff[4];
    #pragma unroll
    for (int n = 0; n < 4; ++n)
        boff[n] = (wc * 64 + n * 16 + l15) * 32 + bsl;
    const int a0base = l15 * 256;
    const int a1base = (16 + l15) * 256;

    f32x4 acc[2][4];
    #pragma unroll
    for (int m = 0; m < 2; ++m)
        #pragma unroll
        for (int n = 0; n < 4; ++n) acc[m][n] = (f32x4){0.f, 0.f, 0.f, 0.f};

    __syncthreads();
    int cur = 0;
    #pragma unroll
    for (int ks = 0; ks < 8; ++ks) {
        if (ks < 7) stage_b(W1, &Bs[cur ^ 1][0], (ks + 1) * 32, t);
        const int ko = ((ks * 4 + kb) ^ x7) * 8;
        bf16x8 a0 = *(const bf16x8*)&Xf[a0base + ko];
        bf16x8 a1 = *(const bf16x8*)&Xf[a1base + ko];
        #pragma unroll
        for (int n = 0; n < 4; ++n) {
            bf16x8 b = *(const bf16x8*)&Bs[cur][boff[n]];
            acc[0][n] = __builtin_amdgcn_mfma_f32_16x16x32_bf16(a0, b, acc[0][n], 0, 0, 0);
            acc[1][n] = __builtin_amdgcn_mfma_f32_16x16x32_bf16(a1, b, acc[1][n], 0, 0, 0);
        }
        __syncthreads();
        cur ^= 1;
    }

    stage_b(W2, &Bs[0][0], 0, t);

    float s4[2][4], ss4[2][4];
    #pragma unroll
    for (int m = 0; m < 2; ++m)
        #pragma unroll
        for (int r = 0; r < 4; ++r) { s4[m][r] = 0.f; ss4[m][r] = 0.f; }
    #pragma unroll
    for (int n = 0; n < 4; ++n) {
        float bo = b1v[wc * 64 + n * 16 + l15];
        #pragma unroll
        for (int m = 0; m < 2; ++m)
            #pragma unroll
            for (int r = 0; r < 4; ++r) {
                float v = acc[m][n][r] + bo;
                acc[m][n][r] = v;
                s4[m][r] += v; ss4[m][r] += v * v;
            }
    }
    #pragma unroll
    for (int off = 1; off <= 8; off <<= 1)
        #pragma unroll
        for (int m = 0; m < 2; ++m)
            #pragma unroll
            for (int r = 0; r < 4; ++r) {
                s4[m][r]  += __shfl_xor(s4[m][r], off, 64);
                ss4[m][r] += __shfl_xor(ss4[m][r], off, 64);
            }
    if (l15 == 0) {
        #pragma unroll
        for (int m = 0; m < 2; ++m)
            #pragma unroll
            for (int r = 0; r < 4; ++r) {
                lnred[m * 16 + kb * 4 + r][wc][0] = s4[m][r];
                lnred[m * 16 + kb * 4 + r][wc][1] = ss4[m][r];
            }
    }
    __syncthreads();
    float mean[2][4], rstd[2][4];
    #pragma unroll
    for (int m = 0; m < 2; ++m)
        #pragma unroll
        for (int r = 0; r < 4; ++r) {
            int p = m * 16 + kb * 4 + r;
            float st  = lnred[p][0][0] + lnred[p][1][0] + lnred[p][2][0] + lnred[p][3][0];
            float sst = lnred[p][0][1] + lnred[p][1][1] + lnred[p][2][1] + lnred[p][3][1];
            mean[m][r] = st * (1.f / 256.f);
            float var = sst * (1.f / 256.f) - mean[m][r] * mean[m][r];
            rstd[m][r] = rsqrtf(var + 1e-6f);
        }
    #pragma unroll
    for (int n = 0; n < 4; ++n) {
        int ch = wc * 64 + n * 16 + l15;
        float gv = g[ch], bev = be[ch];
        #pragma unroll
        for (int m = 0; m < 2; ++m)
            #pragma unroll
            for (int r = 0; r < 4; ++r) {
                float y = (acc[m][n][r] - mean[m][r]) * rstd[m][r] * gv + bev;
                if (SILU) y *= sigmoidf_(y);
                int p = m * 16 + kb * 4 + r;
                Mid[p * 256 + (((ch >> 3) ^ (p & 7)) * 8) + (ch & 7)] = (bf16)y;
            }
    }
    __syncthreads();

    f32x4 acc2[2][4];
    #pragma unroll
    for (int m = 0; m < 2; ++m)
        #pragma unroll
        for (int n = 0; n < 4; ++n) acc2[m][n] = (f32x4){0.f, 0.f, 0.f, 0.f};
    cur = 0;
    #pragma unroll
    for (int ks = 0; ks < 8; ++ks) {
        if (ks < 7) stage_b(W2, &Bs[cur ^ 1][0], (ks + 1) * 32, t);
        const int ko = ((ks * 4 + kb) ^ x7) * 8;
        bf16x8 a0 = *(const bf16x8*)&Mid[a0base + ko];
        bf16x8 a1 = *(const bf16x8*)&Mid[a1base + ko];
        #pragma unroll
        for (int n = 0; n < 4; ++n) {
            bf16x8 b = *(const bf16x8*)&Bs[cur][boff[n]];
            acc2[0][n] = __builtin_amdgcn_mfma_f32_16x16x32_bf16(a0, b, acc2[0][n], 0, 0, 0);
            acc2[1][n] = __builtin_amdgcn_mfma_f32_16x16x32_bf16(a1, b, acc2[1][n], 0, 0, 0);
        }
        __syncthreads();
        cur ^= 1;
    }

    if constexpr (MODE == 0) {
        #pragma unroll
        for (int n = 0; n < 4; ++n) {
            int ch = wc * 64 + n * 16 + l15;
            float bo = b2v[ch];
            #pragma unroll
            for (int m = 0; m < 2; ++m)
                #pragma unroll
                for (int r = 0; r < 4; ++r)
                    Xf[(m * 16 + kb * 4 + r) * 256 + ch] = (bf16)(acc2[m][n][r] + bo);
        }
        __syncthreads();
        bf16* Y = (bf16*)Yv;
        const int p = t >> 3, cb = (t & 7) * 32;
        #pragma unroll
        for (int i = 0; i < 4; ++i) {
            bf16x8 v = *(const bf16x8*)&Xf[p * 256 + cb + i * 8];
            *(bf16x8*)&Y[(q0 + p) * C_ + cb + i * 8] = v;
        }
    } else {
        float* Y = (float*)Yv;
        const int bb = (int)(q0 >> 12);
        #pragma unroll
        for (int n = 0; n < 4; ++n) {
            int ch = wc * 64 + n * 16 + l15;
            float bo = b2v[ch];
            #pragma unroll
            for (int m = 0; m < 2; ++m) {
                int pp = (int)(q0 & 4095) + m * 16 + kb * 4;
                f32x4 val = {acc2[m][n][0] + bo, acc2[m][n][1] + bo,
                             acc2[m][n][2] + bo, acc2[m][n][3] + bo};
                *(f32x4*)&Y[((size_t)bb * C_ + ch) * HW + pp] = val;
            }
        }
    }
}

// ---------------------------------------------------------------- fused attn + output_proj, 256 thr, 16 px
// LDS layout (flat, 72768 B, aliased; 2 blocks/CU):
//  attn: uni[100*256]bf16 @0 (51200) | ckl[16][65]f @51200 (4160) | hb[4*64]f @55360 (1024)
//        S[112*17]f @56384 (7616) | fxs[64*17]f @64000 (4352)   [end 68352]
//  conv: Bs0 @56384 (16384, over S/fxs, end 72768) | Bs1 @16384 (over uni)
//        Xg @0 (8192, over uni) | Mid @32768 (8192, over uni) | lnred @40960 (512, over uni)
__global__ __launch_bounds__(256) void attn_out_k(const bf16* __restrict__ px,
                                                  const bf16* __restrict__ spb,
                                                  const bf16* __restrict__ seb,
                                                  const bf16* __restrict__ w1sb,
                                                  const bf16* __restrict__ w1ckb,
                                                  const bf16* __restrict__ w2Tg,
                                                  const float* __restrict__ b1,
                                                  const float* __restrict__ b2,
                                                  const float* __restrict__ g,
                                                  const float* __restrict__ be,
                                                  const float* __restrict__ sk,
                                                  const bf16* __restrict__ wop1,
                                                  const float* __restrict__ ob1,
                                                  const float* __restrict__ og,
                                                  const float* __restrict__ obe,
                                                  const bf16* __restrict__ wop2,
                                                  const float* __restrict__ ob2,
                                                  float* __restrict__ Y)
{
    __shared__ __align__(16) char shm[72768];
    bf16*  uni = (bf16*)(shm);              // [100][256]
    float* ckl = (float*)(shm + 51200);     // [16][65]
    float* hb  = (float*)(shm + 55360);     // [4][64]
    float* S   = (float*)(shm + 56384);     // [112][17]
    float* fxs = (float*)(shm + 64000);     // [64][17]
    bf16*  Bs0 = (bf16*)(shm + 56384);
    bf16*  Bs1 = (bf16*)(shm + 16384);
    bf16*  Xg  = (bf16*)(shm);              // [16][256]
    bf16*  Mid = (bf16*)(shm + 32768);      // [16][256]
    float* lnred = (float*)(shm + 40960);   // [16][4][2]

    const int t = threadIdx.x, lane = t & 63, wid = t >> 6;
    const int l15 = lane & 15, kb = lane >> 4, l31 = lane & 31;
    const int blk = blockIdx.x;
    const int batch = blk >> 8, tt = blk & 255;
    const int h0 = (tt >> 4) * 4, w0 = (tt & 15) * 4;
    const long base = (long)batch * HW;

    // hoist small per-lane params BEFORE any global_load_lds
    const float bo  = (lane < NN) ? b1[lane] : 0.f;
    const float gl  = (lane < NN) ? g[lane] : 0.f;
    const float bel = (lane < NN) ? be[lane] : 0.f;
    const float b2l = (lane < NN) ? b2[lane] : 0.f;
    const float skv = (lane < NN) ? sk[lane] : 0.f;
    const int nn_ = (lane < NN) ? lane : 0;
    const int dy = nn_ / 7, dx = nn_ % 7;

    // ---- stage FULL spat union (100 rows x 256 ch), linear, both source & dest
    #pragma unroll
    for (int i = 0; i < 13; ++i) {
        int st = i * 256 + t;
        if (st < 3200) {
            int u = st >> 5, s = st & 31;
            int uy = (u * 205) >> 11, ux = u - uy * 10;
            long grow = base + refl(h0 + uy - 3) * 64 + refl(w0 + ux - 3);
            GLD16(spb + grow * C_ + s * 8, &uni[u * 256 + s * 8]);
        }
    }

    // ---- sim + fxsem MFMA, operands straight from global (L2-resident)
    const int ppy = l15 >> 2, ppx = l15 & 3;
    const long qB = base + (h0 + ppy) * 64 + (w0 + ppx);
    const bf16* bpxp = px + qB * C_ + kb * 8;
    const bf16* bsemp = seb + qB * C_ + kb * 8;

    bool valid[3], ispx[3];
    const bf16* arow[3];
    #pragma unroll
    for (int j = 0; j < 3; ++j) {
        int tid = wid + 4 * j;
        valid[j] = tid < 11;
        ispx[j] = tid < 7;
        int u = tid * 16 + l15;
        int uy = (u * 205) >> 11, ux = u - uy * 10;
        long grow = (u < 100) ? base + refl(h0 + uy - 3) * 64 + refl(w0 + ux - 3) : base;
        int o = ((tid - 7) & 3) * 16 + l15;
        arow[j] = ispx[j] ? (px + grow * C_ + kb * 8)
                          : (w1sb + (size_t)o * C_ + kb * 8);
    }

    f32x4 acc[3];
    #pragma unroll
    for (int j = 0; j < 3; ++j) acc[j] = (f32x4){0.f, 0.f, 0.f, 0.f};

    #pragma unroll
    for (int ks = 0; ks < 8; ++ks) {
        bf16x8 bp = *(const bf16x8*)(bpxp + ks * 32);
        bf16x8 bs = *(const bf16x8*)(bsemp + ks * 32);
        #pragma unroll
        for (int j = 0; j < 3; ++j) {
            if (valid[j]) {
                bf16x8 a = *(const bf16x8*)(arow[j] + ks * 32);
                acc[j] = __builtin_amdgcn_mfma_f32_16x16x32_bf16(a, ispx[j] ? bp : bs, acc[j], 0, 0, 0);
            }
        }
    }

    // fixup weight registers: coalesced 128B reads (2B/lane), L2-resident
    float w1r[NN], w2r[NN];
    #pragma unroll
    for (int k = 0; k < NN; ++k) {
        w1r[k] = (float)w1ckb[k * 64 + lane];
        w2r[k] = (float)w2Tg[k * 64 + lane];
    }

    // D: row = a-rows (u / o), col = pixel (l15)
    #pragma unroll
    for (int j = 0; j < 3; ++j) {
        if (valid[j]) {
            int tid = wid + 4 * j;
            float* dst = ispx[j] ? &S[(tid * 16 + kb * 4) * 17 + l15]
                                 : &fxs[(((tid - 7) * 16) + kb * 4) * 17 + l15];
            dst[0] = acc[j][0]; dst[17] = acc[j][1]; dst[34] = acc[j][2]; dst[51] = acc[j][3];
        }
    }
    __syncthreads();   // B1: S/fxs visible; uni staging drained (vmcnt0 at barrier)

    // ---- softmax over 49 neighbors (wave -> 4 pixels)
    #pragma unroll
    for (int j = 0; j < 4; ++j) {
        int p = wid * 4 + j, py = p >> 2, px4 = p & 3;
        int u = (py + dy) * 10 + px4 + dx;
        float sval = (lane < NN) ? S[u * 17 + p] * 0.0625f : -1e30f;
        float mx = sval;
        #pragma unroll
        for (int off = 32; off; off >>= 1) mx = fmaxf(mx, __shfl_xor(mx, off, 64));
        float ev = (lane < NN) ? __expf(sval - mx) : 0.f;
        float ssum = ev;
        #pragma unroll
        for (int off = 32; off; off >>= 1) ssum += __shfl_xor(ssum, off, 64);
        ckl[p * 65 + lane] = (lane < NN) ? (ev / ssum) * skv : 0.f;
    }

    // ---- fixup: fx = fxs + W1ck.ck + b1 -> LN49+SiLU -> conv49 -> gate -> renorm
    #pragma unroll
    for (int j = 0; j < 4; ++j) {
        int p = wid * 4 + j;
        float fxa = 0.f, fxb = 0.f;
        #pragma unroll
        for (int k = 0; k < 48; k += 2) {
            fxa += w1r[k] * ckl[p * 65 + k];
            fxb += w1r[k + 1] * ckl[p * 65 + k + 1];
        }
        fxa += w1r[48] * ckl[p * 65 + 48];
        float fx = fxs[lane * 17 + p] + bo + fxa + fxb;
        float s = fx, ss = fx * fx;
        #pragma unroll
        for (int off = 32; off; off >>= 1) {
            s  += __shfl_xor(s, off, 64);
            ss += __shfl_xor(ss, off, 64);
        }
        float mean = s * (1.f / 49.f);
        float var  = ss * (1.f / 49.f) - mean * mean;
        float rstd = rsqrtf(var + 1e-6f);
        float hv = 0.f;
        if (lane < NN) {
            float xn = (fx - mean) * rstd * gl + bel;
            hv = xn * sigmoidf_(xn);
        }
        hb[wid * 64 + lane] = hv;
        float ckv = 0.f;
        if (lane < NN) {
            float ca = 0.f, cb = 0.f;
            #pragma unroll
            for (int k = 0; k < 48; k += 2) {
                ca += w2r[k] * hb[wid * 64 + k];
                cb += w2r[k + 1] * hb[wid * 64 + k + 1];
            }
            ca += w2r[48] * hb[wid * 64 + 48];
            ckv = ckl[p * 65 + lane] * (1.f + sigmoidf_(b2l + ca + cb));
        }
        float tot = ckv;
        #pragma unroll
        for (int off = 32; off; off >>= 1) tot += __shfl_xor(tot, off, 64);
        ckl[p * 65 + lane] = (lane < NN) ? ckv / (tot + 1e-7f) : 0.f;
    }
    __syncthreads();   // B2: all S/fxs reads done -> Bs0 region safe to overwrite

    // issue W1 chunk0 staging; overlaps gather
    stage_b(wop1, Bs0, 0, t);

    // ---- gather: half-wave (32 lanes) per pixel, full 512B LDS rows, conflict-free, no barriers
    bf16x8 ov[2];
    #pragma unroll
    for (int j = 0; j < 2; ++j) {
        const int gp = wid * 4 + j * 2 + (lane >> 5);
        const int ub = (gp >> 2) * 10 + (gp & 3);
        float a[8];
        #pragma unroll
        for (int e = 0; e < 8; ++e) a[e] = 0.f;
        #pragma unroll
        for (int dyy = 0; dyy < 7; ++dyy) {
            bf16x8 v[7];
            #pragma unroll
            for (int dxx = 0; dxx < 7; ++dxx) {
                int u = ub + dyy * 10 + dxx;
                v[dxx] = *(const bf16x8*)&uni[u * 256 + l31 * 8];
            }
            #pragma unroll
            for (int dxx = 0; dxx < 7; ++dxx) {
                float cv = ckl[gp * 65 + dyy * 7 + dxx];
                #pragma unroll
                for (int e = 0; e < 8; ++e) a[e] += cv * (float)v[dxx][e];
            }
        }
        #pragma unroll
        for (int e = 0; e < 8; ++e) ov[j][e] = (bf16)a[e];
    }
    __syncthreads();   // B3: gather uni reads done -> uni dead (Xg/Bs1/Mid safe); Bs0 drained

    // write gathered pixels to Xg (swizzled rows for conv A-reads)
    #pragma unroll
    for (int j = 0; j < 2; ++j) {
        const int gp = wid * 4 + j * 2 + (lane >> 5);
        *(bf16x8*)&Xg[gp * 256 + ((l31 ^ (gp & 7)) * 8)] = ov[j];
    }
    __syncthreads();   // B4: Xg visible to all waves

    // ================= output_proj: conv -> LN -> conv, on the 16 gathered pixels =================
    const int x7 = l15 & 7;
    const int bsl = (kb ^ ((l15 >> 1) & 3)) * 8;
    int boff[4];
    #pragma unroll
    for (int n = 0; n < 4; ++n)
        boff[n] = (wid * 64 + n * 16 + l15) * 32 + bsl;

    f32x4 cacc[4];
    #pragma unroll
    for (int n = 0; n < 4; ++n) cacc[n] = (f32x4){0.f, 0.f, 0.f, 0.f};

    int cur = 0;
    #pragma unroll
    for (int ks = 0; ks < 8; ++ks) {
        if (ks < 7) stage_b(wop1, cur ? Bs0 : Bs1, (ks + 1) * 32, t);
        const int ko = ((ks * 4 + kb) ^ x7) * 8;
        bf16x8 a = *(const bf16x8*)&Xg[l15 * 256 + ko];
        #pragma unroll
        for (int n = 0; n < 4; ++n) {
            bf16x8 b = *(const bf16x8*)&((cur ? Bs1 : Bs0)[boff[n]]);
            cacc[n] = __builtin_amdgcn_mfma_f32_16x16x32_bf16(a, b, cacc[n], 0, 0, 0);
        }
        __syncthreads();
        cur ^= 1;
    }

    stage_b(wop2, Bs0, 0, t);   // overlap with LN phase

    // bias + per-pixel LN (pixel = kb*4 + r, ch = wid*64 + n*16 + l15)
    float s4[4] = {0.f, 0.f, 0.f, 0.f}, ss4[4] = {0.f, 0.f, 0.f, 0.f};
    #pragma unroll
    for (int n = 0; n < 4; ++n) {
        float bv = ob1[wid * 64 + n * 16 + l15];
        #pragma unroll
        for (int r = 0; r < 4; ++r) {
            float v = cacc[n][r] + bv;
            cacc[n][r] = v;
            s4[r] += v; ss4[r] += v * v;
        }
    }
    #pragma unroll
    for (int off = 1; off <= 8; off <<= 1)
        #pragma unroll
        for (int r = 0; r < 4; ++r) {
            s4[r]  += __shfl_xor(s4[r], off, 64);
            ss4[r] += __shfl_xor(ss4[r], off, 64);
        }
    if (l15 == 0) {
        #pragma unroll
        for (int r = 0; r < 4; ++r) {
            lnred[((kb * 4 + r) * 4 + wid) * 2 + 0] = s4[r];
            lnred[((kb * 4 + r) * 4 + wid) * 2 + 1] = ss4[r];
        }
    }
    __syncthreads();
    float mean[4], rstd[4];
    #pragma unroll
    for (int r = 0; r < 4; ++r) {
        int p = kb * 4 + r;
        float st  = lnred[(p * 4 + 0) * 2] + lnred[(p * 4 + 1) * 2] + lnred[(p * 4 + 2) * 2] + lnred[(p * 4 + 3) * 2];
        float sst = lnred[(p * 4 + 0) * 2 + 1] + lnred[(p * 4 + 1) * 2 + 1] + lnred[(p * 4 + 2) * 2 + 1] + lnred[(p * 4 + 3) * 2 + 1];
        mean[r] = st * (1.f / 256.f);
        float var = sst * (1.f / 256.f) - mean[r] * mean[r];
        rstd[r] = rsqrtf(var + 1e-6f);
    }
    #pragma unroll
    for (int n = 0; n < 4; ++n) {
        int ch = wid * 64 + n * 16 + l15;
        float gv = og[ch], bev = obe[ch];
        #pragma unroll
        for (int r = 0; r < 4; ++r) {
            float y = (cacc[n][r] - mean[r]) * rstd[r] * gv + bev;
            int p = kb * 4 + r;
            Mid[p * 256 + (((ch >> 3) ^ (p & 7)) * 8) + (ch & 7)] = (bf16)y;
        }
    }
    __syncthreads();   // Mid + Bs0 (W2 chunk0) ready

    f32x4 cacc2[4];
    #pragma unroll
    for (int n = 0; n < 4; ++n) cacc2[n] = (f32x4){0.f, 0.f, 0.f, 0.f};
    cur = 0;
    #pragma unroll
    for (int ks = 0; ks < 8; ++ks) {
        if (ks < 7) stage_b(wop2, cur ? Bs0 : Bs1, (ks + 1) * 32, t);
        const int ko = ((ks * 4 + kb) ^ x7) * 8;
        bf16x8 a = *(const bf16x8*)&Mid[l15 * 256 + ko];
        #pragma unroll
        for (int n = 0; n < 4; ++n) {
            bf16x8 b = *(const bf16x8*)&((cur ? Bs1 : Bs0)[boff[n]]);
            cacc2[n] = __builtin_amdgcn_mfma_f32_16x16x32_bf16(a, b, cacc2[n], 0, 0, 0);
        }
        __syncthreads();
        cur ^= 1;
    }

    // final write: fp32 channel-first; pixel p = kb*4+r -> (py=kb, pxc=r) => f32x4 over r
    {
        const size_t rowbase = ((size_t)batch * C_) * HW + (size_t)(h0 + kb) * 64 + w0;
        #pragma unroll
        for (int n = 0; n < 4; ++n) {
            int ch = wid * 64 + n * 16 + l15;
            float bv = ob2[ch];
            f32x4 val = {cacc2[n][0] + bv, cacc2[n][1] + bv, cacc2[n][2] + bv, cacc2[n][3] + bv};
            *(f32x4*)&Y[rowbase + (size_t)ch * HW] = val;
        }
    }
}

// ---------------------------------------------------------------- launch
extern "C" void kernel_launch(void* const* d_in, const int* in_sizes, int n_in,
                              void* d_out, int out_size, void* d_ws, size_t ws_size,
                              hipStream_t stream)
{
    const float* spatial  = (const float*)d_in[0];
    const float* semantic = (const float*)d_in[1];
    const float* rp_w1 = (const float*)d_in[2];
    const float* rp_b1 = (const float*)d_in[3];
    const float* rp_g  = (const float*)d_in[4];
    const float* rp_be = (const float*)d_in[5];
    const float* rp_w2 = (const float*)d_in[6];
    const float* rp_b2 = (const float*)d_in[7];
    const float* fp_w1 = (const float*)d_in[8];
    const float* fp_b1 = (const float*)d_in[9];
    const float* fp_g  = (const float*)d_in[10];
    const float* fp_be = (const float*)d_in[11];
    const float* fp_w2 = (const float*)d_in[12];
    const float* fp_b2 = (const float*)d_in[13];
    const float* op_w1 = (const float*)d_in[14];
    const float* op_b1 = (const float*)d_in[15];
    const float* op_g  = (const float*)d_in[16];
    const float* op_be = (const float*)d_in[17];
    const float* op_w2 = (const float*)d_in[18];
    const float* op_b2 = (const float*)d_in[19];
    const float* sigma = (const float*)d_in[20];

    const size_t NPX = 2 * (size_t)HW;          // 8192 pixels
    float* ws = (float*)d_ws;
    float* sk    = ws;                           // 64
    bf16* bfbase = (bf16*)(sk + 64);
    bf16* spb = bfbase;                          // [8192][256]
    bf16* seb = spb + NPX * C_;
    bf16* t1  = seb + NPX * C_;
    bf16* wrp1 = t1 + NPX * C_;
    bf16* wrp2 = wrp1 + C_ * C_;
    bf16* wop1 = wrp2 + C_ * C_;
    bf16* wop2 = wop1 + C_ * C_;
    bf16* w1sb = wop2 + C_ * C_;                 // [64][256]
    bf16* w2Tg = w1sb + 64 * C_;                 // [49][64] pad 3200
    bf16* w1ckb = w2Tg + 3200;                   // [49][64] pad 3200

    setup_k<<<4443, 256, 0, stream>>>(spatial, semantic, rp_w1, rp_w2, op_w1, op_w2,
                                      fp_w1, fp_w2, sigma,
                                      spb, seb, wrp1, wrp2, wop1, wop2,
                                      w1ckb, w1sb, w2Tg, sk);

    // range_proj fused pair: conv+bias -> LN+SiLU -> conv+bias  => t1 = px
    conv_pair<true, 0><<<256, 256, 0, stream>>>(seb, wrp1, rp_b1, rp_g, rp_be, wrp2, rp_b2, t1);

    // attn (sim MFMA + softmax + fixup + gather) fused with output_proj -> d_out
    attn_out_k<<<512, 256, 0, stream>>>(t1, spb, seb, w1sb, w1ckb, w2Tg, fp_b1, fp_b2,
                                        fp_g, fp_be, sk,
                                        wop1, op_b1, op_g, op_be, wop2, op_b2,
                                        (float*)d_out);
}